// Round 12
// baseline (286.167 us; speedup 1.0000x reference)
//
#include <hip/hip_runtime.h>
#include <hip/hip_fp16.h>

#define DIM 64
#define BSH 8                 // log2(nodes per bucket) = 256 nodes/bucket
#define BMASK 255u
#define NBMAX 1024            // max coarse buckets supported
#define BINC 12288            // edges staged per bin block (LDS budget 136KB)
#define BSTRIDE 8192          // fixed arena per bucket (avg 6826, >10 sigma margin)

// ---------------- prep kernels ----------------

__global__ void zero_ints(int* __restrict__ p, int n) {
    int i = blockIdx.x * blockDim.x + threadIdx.x;
    if (i < n) p[i] = 0;
}

// Single-read LDS-staged scatter into fixed-stride bucket arenas.
// entry = (row<<8)|(col&255); bucket id staged as u16 alongside.
__global__ __launch_bounds__(1024) void bin_kernel(const int* __restrict__ edge, int E,
                                                   int* __restrict__ bcur,
                                                   unsigned* __restrict__ bin, int NB) {
    __shared__ unsigned ent[BINC];
    __shared__ unsigned short bkt[BINC];
    __shared__ unsigned stage[BINC];
    __shared__ int lcnt[NBMAX];
    __shared__ int lsc[NBMAX];
    __shared__ int lcur[NBMAX];
    __shared__ int gb[NBMAX];
    const int tid = (int)threadIdx.x;
    const int beg = (int)blockIdx.x * BINC;
    const int n = min(BINC, E - beg);

    lcnt[tid] = 0;
    __syncthreads();
    // phase 1: single global read of (row, col); stage entry+bucket, count
    for (int i = tid; i < n; i += 1024) {
        int r = edge[beg + i];
        int c = edge[E + beg + i];
        int b = c >> BSH;
        ent[i] = ((unsigned)r << BSH) | ((unsigned)c & BMASK);
        bkt[i] = (unsigned short)b;
        atomicAdd(&lcnt[b], 1);
    }
    __syncthreads();
    // inclusive scan over 1024 slots
    lsc[tid] = lcnt[tid];
    __syncthreads();
    for (int off = 1; off < 1024; off <<= 1) {
        int t = (tid >= off) ? lsc[tid - off] : 0;
        __syncthreads();
        lsc[tid] += t;
        __syncthreads();
    }
    // reserve per-bucket global ranges (fixed-stride arenas)
    {
        int cb = lcnt[tid];
        lcur[tid] = lsc[tid] - cb;
        if (tid < NB) gb[tid] = cb ? atomicAdd(&bcur[tid], cb) : 0;
    }
    __syncthreads();
    // phase 2: rank into LDS stage (sorted by bucket), all from LDS
    for (int i = tid; i < n; i += 1024) {
        int b = (int)bkt[i];
        int slot = atomicAdd(&lcur[b], 1);
        stage[slot] = ent[i];
    }
    __syncthreads();
    // phase 3: per-bucket coalesced copy out into the bucket arena
    const int wid = tid >> 6, lane = tid & 63;
    for (int b = wid; b < NB; b += 16) {
        int cb = lcnt[b];
        if (!cb) continue;
        int lb = lsc[b] - cb;
        int g = b * BSTRIDE + gb[b];
        for (int l = lane; l < cb; l += 64)
            bin[g + l] = stage[lb + l];
    }
}

// per-bucket counting sort (bin staged in LDS once) -> CSR + pdesc(float4) +
// fused y0 init (y0 = fp16(dinv * emb))
__global__ __launch_bounds__(256) void csr_kernel(const unsigned* __restrict__ bin,
                                                  const int* __restrict__ bcnt,
                                                  const float* __restrict__ user,
                                                  const float* __restrict__ item,
                                                  int nU,
                                                  float4* __restrict__ pdesc,
                                                  int* __restrict__ row_sorted,
                                                  __half* __restrict__ y0,
                                                  int nN) {
    __shared__ unsigned sbin[BSTRIDE];
    __shared__ int lcnt[256];
    __shared__ int lsc[256];
    __shared__ int lcur[256];
    __shared__ float sdinv[256];
    const int tid = (int)threadIdx.x;
    const int b = (int)blockIdx.x;
    const int abase = b * BSTRIDE;
    const int cnt = bcnt[b];
    lcnt[tid] = 0;
    // stage this bucket's entries in LDS (single global read)
    for (int i = tid; i < cnt; i += 256)
        sbin[i] = bin[abase + i];
    __syncthreads();
    for (int i = tid; i < cnt; i += 256)
        atomicAdd(&lcnt[sbin[i] & BMASK], 1);
    __syncthreads();
    lsc[tid] = lcnt[tid];
    __syncthreads();
    for (int off = 1; off < 256; off <<= 1) {
        int t = (tid >= off) ? lsc[tid - off] : 0;
        __syncthreads();
        lsc[tid] += t;
        __syncthreads();
    }
    const int cb = lcnt[tid];
    const int lb = lsc[tid] - cb;
    lcur[tid] = abase + lb;
    float dv = cb ? rsqrtf((float)cb) : 0.0f;
    sdinv[tid] = dv;
    int node = (b << BSH) + tid;
    if (node < nN) {
        float4 pd;
        pd.x = __int_as_float(abase + lb);
        pd.y = __int_as_float(cb);
        pd.z = dv;
        pd.w = cb ? sqrtf((float)cb) : 0.0f;
        pdesc[node] = pd;
    }
    __syncthreads();
    for (int i = tid; i < cnt; i += 256) {
        unsigned e = sbin[i];
        int c = (int)(e & BMASK);
        int p = atomicAdd(&lcur[c], 1);
        row_sorted[p] = (int)(e >> BSH);
    }
    // fused y0 init: 256 nodes x 8 chunks; chunk qc covers dims 8qc..8qc+7
    const int baseNode = b << BSH;
#pragma unroll
    for (int it = 0; it < 8; ++it) {
        int idx = it * 256 + tid;
        int ln = idx >> 3;
        int node2 = baseNode + ln;
        if (node2 < nN) {
            int qc = idx & 7;
            const float* src = (node2 < nU) ? user + (size_t)node2 * DIM
                                            : item + (size_t)(node2 - nU) * DIM;
            float4 e0 = ((const float4*)src)[qc * 2];
            float4 e1 = ((const float4*)src)[qc * 2 + 1];
            float dvn = sdinv[ln];
            float4 pack;
            __half2* p = (__half2*)&pack;
            p[0] = __floats2half2_rn(dvn * e0.x, dvn * e0.y);
            p[1] = __floats2half2_rn(dvn * e0.z, dvn * e0.w);
            p[2] = __floats2half2_rn(dvn * e1.x, dvn * e1.y);
            p[3] = __floats2half2_rn(dvn * e1.z, dvn * e1.w);
            ((float4*)y0)[(size_t)baseNode * 8 + idx] = pack;
        }
    }
}

// zero the shared pad row (row nN) of the three y tables
__global__ void zero_row_kernel(__half* __restrict__ r1, __half* __restrict__ r2,
                                __half* __restrict__ r3, int nN) {
    int t = threadIdx.x;       // 64 threads
    size_t o = (size_t)nN * DIM + t;
    r1[o] = __float2half(0.0f);
    r2[o] = __float2half(0.0f);
    r3[o] = __float2half(0.0f);
}

// one wave per node; 8 edge-slots x 8 lanes; lane loads float4 (8 halves);
// 32 edges (4KB) in flight; tail slots gather the shared zero row (index nN)
// -> maskless packed-fp16 accumulate.
// LAST fuses the final combine using emb = rdinv*y0 (fallback load if deg==0):
// out = 0.25*(emb + rdinv*(y1+y2) + dinv*sum).
template<bool LAST>
__global__ __launch_bounds__(256) void layer_kernel(const float4* __restrict__ pdesc,
                                                    const int* __restrict__ row_sorted,
                                                    const __half* __restrict__ y_in,
                                                    __half* __restrict__ y_out,
                                                    const float* __restrict__ user,
                                                    const float* __restrict__ item,
                                                    const __half* __restrict__ y_zero,
                                                    const __half* __restrict__ y_prev,
                                                    float* __restrict__ out,
                                                    int nU, int nN) {
    int wave = (int)((blockIdx.x * blockDim.x + threadIdx.x) >> 6);
    int lane = (int)(threadIdx.x & 63);
    if (wave >= nN) return;
    const float4 pd = pdesc[wave];
    const int beg = __float_as_int(pd.x);
    const int n = __float_as_int(pd.y);
    const float dc = pd.z;
    const float rd = pd.w;
    const int zrow = nN;
    const int g = lane >> 3;   // edge slot 0..7
    const int q = lane & 7;    // 16B chunk of the row, 0..7
    const float4* yv = (const float4*)y_in;
    __half2 acc0 = __float2half2_rn(0.0f);
    __half2 acc1 = acc0, acc2 = acc0, acc3 = acc0;
    for (int base = 0; base < n; base += 32) {
        int s = base + g;
        int e = beg + s;
        int i0 = (s      < n) ? row_sorted[e]      : zrow;
        int i1 = (s + 8  < n) ? row_sorted[e + 8]  : zrow;
        int i2 = (s + 16 < n) ? row_sorted[e + 16] : zrow;
        int i3 = (s + 24 < n) ? row_sorted[e + 24] : zrow;
        float4 v0 = yv[(size_t)i0 * 8 + q];
        float4 v1 = yv[(size_t)i1 * 8 + q];
        float4 v2 = yv[(size_t)i2 * 8 + q];
        float4 v3 = yv[(size_t)i3 * 8 + q];
        const __half2* h0 = (const __half2*)&v0;
        const __half2* h1 = (const __half2*)&v1;
        const __half2* h2 = (const __half2*)&v2;
        const __half2* h3 = (const __half2*)&v3;
        acc0 = __hadd2(acc0, h0[0]); acc1 = __hadd2(acc1, h0[1]);
        acc2 = __hadd2(acc2, h0[2]); acc3 = __hadd2(acc3, h0[3]);
        acc0 = __hadd2(acc0, h1[0]); acc1 = __hadd2(acc1, h1[1]);
        acc2 = __hadd2(acc2, h1[2]); acc3 = __hadd2(acc3, h1[3]);
        acc0 = __hadd2(acc0, h2[0]); acc1 = __hadd2(acc1, h2[1]);
        acc2 = __hadd2(acc2, h2[2]); acc3 = __hadd2(acc3, h2[3]);
        acc0 = __hadd2(acc0, h3[0]); acc1 = __hadd2(acc1, h3[1]);
        acc2 = __hadd2(acc2, h3[2]); acc3 = __hadd2(acc3, h3[3]);
    }
    // reduce across the 8 edge-slots (lane bits 3..5), packed fp16
#pragma unroll
    for (int ofs = 8; ofs <= 32; ofs <<= 1) {
        int t0 = __shfl_xor(*reinterpret_cast<int*>(&acc0), ofs);
        int t1 = __shfl_xor(*reinterpret_cast<int*>(&acc1), ofs);
        int t2 = __shfl_xor(*reinterpret_cast<int*>(&acc2), ofs);
        int t3 = __shfl_xor(*reinterpret_cast<int*>(&acc3), ofs);
        acc0 = __hadd2(acc0, *reinterpret_cast<__half2*>(&t0));
        acc1 = __hadd2(acc1, *reinterpret_cast<__half2*>(&t1));
        acc2 = __hadd2(acc2, *reinterpret_cast<__half2*>(&t2));
        acc3 = __hadd2(acc3, *reinterpret_cast<__half2*>(&t3));
    }
    if (g == 0) {
        float2 s0 = __half22float2(acc0);
        float2 s1 = __half22float2(acc1);
        float2 s2 = __half22float2(acc2);
        float2 s3 = __half22float2(acc3);
        if (!LAST) {
            float s = dc * dc;          // y_out = dinv * (dinv * sum)
            float4 pack;
            __half2* ph = (__half2*)&pack;
            ph[0] = __floats2half2_rn(s * s0.x, s * s0.y);
            ph[1] = __floats2half2_rn(s * s1.x, s * s1.y);
            ph[2] = __floats2half2_rn(s * s2.x, s * s2.y);
            ph[3] = __floats2half2_rn(s * s3.x, s * s3.y);
            ((float4*)y_out)[(size_t)wave * 8 + q] = pack;
        } else {
            // out = 0.25*(emb + rdinv*(y1+y2) + dinv*sum); emb = rdinv*y0
            float4 y1r = ((const float4*)y_prev)[(size_t)wave * 8 + q];
            float4 y2r = ((const float4*)y_in)[(size_t)wave * 8 + q];
            const __half2* p1 = (const __half2*)&y1r;
            const __half2* p2 = (const __half2*)&y2r;
            float w[8];
#pragma unroll
            for (int j = 0; j < 4; ++j) {
                float2 u1 = __half22float2(p1[j]);
                float2 u2 = __half22float2(p2[j]);
                w[2 * j]     = u1.x + u2.x;
                w[2 * j + 1] = u1.y + u2.y;
            }
            float emb[8];
            if (rd != 0.0f) {
                float4 y0r = ((const float4*)y_zero)[(size_t)wave * 8 + q];
                const __half2* p0 = (const __half2*)&y0r;
#pragma unroll
                for (int j = 0; j < 4; ++j) {
                    float2 u0 = __half22float2(p0[j]);
                    emb[2 * j]     = rd * u0.x;
                    emb[2 * j + 1] = rd * u0.y;
                }
            } else {
                const float* src = (wave < nU) ? user + (size_t)wave * DIM
                                               : item + (size_t)(wave - nU) * DIM;
                float4 e0 = ((const float4*)src)[q * 2];
                float4 e1 = ((const float4*)src)[q * 2 + 1];
                emb[0] = e0.x; emb[1] = e0.y; emb[2] = e0.z; emb[3] = e0.w;
                emb[4] = e1.x; emb[5] = e1.y; emb[6] = e1.z; emb[7] = e1.w;
            }
            float4 o0, o1;
            o0.x = 0.25f * (emb[0] + rd * w[0] + dc * s0.x);
            o0.y = 0.25f * (emb[1] + rd * w[1] + dc * s0.y);
            o0.z = 0.25f * (emb[2] + rd * w[2] + dc * s1.x);
            o0.w = 0.25f * (emb[3] + rd * w[3] + dc * s1.y);
            o1.x = 0.25f * (emb[4] + rd * w[4] + dc * s2.x);
            o1.y = 0.25f * (emb[5] + rd * w[5] + dc * s2.y);
            o1.z = 0.25f * (emb[6] + rd * w[6] + dc * s3.x);
            o1.w = 0.25f * (emb[7] + rd * w[7] + dc * s3.y);
            float4* o4 = (float4*)(out + (size_t)wave * DIM + q * 8);
            o4[0] = o0;
            o4[1] = o1;
        }
    }
}

// ---------------- host launcher ----------------

extern "C" void kernel_launch(void* const* d_in, const int* in_sizes, int n_in,
                              void* d_out, int out_size, void* d_ws, size_t ws_size,
                              hipStream_t stream) {
    const float* user = (const float*)d_in[0];
    const float* item = (const float*)d_in[1];
    const int*   edge = (const int*)d_in[2];

    const int nU = in_sizes[0] / DIM;
    const int nI = in_sizes[1] / DIM;
    const int nN = nU + nI;
    const int E  = in_sizes[2] / 2;
    const int NB = (nN + 255) / 256;     // 256-node coarse buckets

    float* out = (float*)d_out;

    // workspace carve-up (256B aligned)
    char* ws = (char*)d_ws;
    size_t off = 0;
    auto take = [&](size_t bytes) -> char* {
        char* p = ws + off;
        off = (off + bytes + 255) & ~(size_t)255;
        return p;
    };
    const size_t ytab = (size_t)(nN + 1) * DIM * 2;      // fp16 table + zero row
    const size_t arena = (size_t)NB * BSTRIDE * 4;       // fixed-stride arena
    int*      bcur       = (int*)   take((size_t)NB * 4);
    float4*   pdesc      = (float4*)take((size_t)nN * 16);
    int*      row_sorted = (int*)   take(arena);
    char*     R1 = take(arena > ytab ? arena : ytab);    // bin, then y1
    char*     R2 = take(ytab);                           // y0
    char*     R3 = take(ytab);                           // y2
    unsigned* bin = (unsigned*)R1;
    __half*   y1  = (__half*)R1;
    __half*   y0  = (__half*)R2;
    __half*   y2  = (__half*)R3;
    (void)ws_size; (void)n_in; (void)out_size;

    const int B = 256;
    dim3 blk(B);

    // 1. zero bucket cursors
    zero_ints<<<dim3((NB + B - 1) / B), blk, 0, stream>>>(bcur, NB);
    // 2. single-read LDS-staged scatter into fixed-stride bucket arenas
    bin_kernel<<<dim3((E + BINC - 1) / BINC), dim3(1024), 0, stream>>>(edge, E, bcur, bin, NB);
    // 3. per-bucket counting sort -> CSR + pdesc + fused y0 init
    csr_kernel<<<dim3(NB), blk, 0, stream>>>(bin, bcur, user, item, nU,
                                             pdesc, row_sorted, y0, nN);
    // 3b. zero the shared pad row (after bin is consumed; y1 aliases bin)
    zero_row_kernel<<<dim3(1), dim3(64), 0, stream>>>(y0, y1, y2, nN);

    // 4. three propagation layers; layer 3 fuses the final combine
    dim3 lgrid((nN + 3) / 4);   // 4 waves (nodes) per 256-thread block
    layer_kernel<false><<<lgrid, blk, 0, stream>>>(pdesc, row_sorted, y0, y1,
                                                   nullptr, nullptr, nullptr, nullptr, nullptr,
                                                   nU, nN);
    layer_kernel<false><<<lgrid, blk, 0, stream>>>(pdesc, row_sorted, y1, y2,
                                                   nullptr, nullptr, nullptr, nullptr, nullptr,
                                                   nU, nN);
    layer_kernel<true ><<<lgrid, blk, 0, stream>>>(pdesc, row_sorted, y2, nullptr,
                                                   user, item, y0, y1, out,
                                                   nU, nN);
}

// Round 13
// 275.624 us; speedup vs baseline: 1.0383x; 1.0383x over previous
//
#include <hip/hip_runtime.h>
#include <hip/hip_fp16.h>

#define DIM 64
#define BSH 8                 // log2(nodes per bucket) = 256 nodes/bucket
#define BMASK 255u
#define NBMAX 1024            // max coarse buckets supported
#define BINC 16384            // edges staged per bin block (80KB LDS, 2 blocks/CU)
#define BSTRIDE 8192          // fixed arena per bucket (avg 6826, >10 sigma margin)

// ---------------- prep kernels ----------------

__global__ void zero_ints(int* __restrict__ p, int n) {
    int i = blockIdx.x * blockDim.x + threadIdx.x;
    if (i < n) p[i] = 0;
}

// LDS-staged scatter into fixed-stride bucket arenas; entry = (row<<8)|(col&255).
// Reserves one contiguous range per (block,bucket) with a single global atomic.
__global__ __launch_bounds__(1024) void bin_kernel(const int* __restrict__ edge, int E,
                                                   int* __restrict__ bcur,
                                                   unsigned* __restrict__ bin, int NB) {
    __shared__ unsigned stage[BINC];
    __shared__ int lcnt[NBMAX];
    __shared__ int lsc[NBMAX];
    __shared__ int lcur[NBMAX];
    __shared__ int gb[NBMAX];
    const int tid = (int)threadIdx.x;
    const int beg = (int)blockIdx.x * BINC;
    const int n = min(BINC, E - beg);

    lcnt[tid] = 0;
    __syncthreads();
    // phase 1: count per bucket
    for (int i = tid; i < n; i += 1024)
        atomicAdd(&lcnt[edge[E + beg + i] >> BSH], 1);
    __syncthreads();
    // inclusive scan over 1024 slots
    lsc[tid] = lcnt[tid];
    __syncthreads();
    for (int off = 1; off < 1024; off <<= 1) {
        int t = (tid >= off) ? lsc[tid - off] : 0;
        __syncthreads();
        lsc[tid] += t;
        __syncthreads();
    }
    // reserve per-bucket global ranges (fixed-stride arenas)
    {
        int cb = lcnt[tid];
        lcur[tid] = lsc[tid] - cb;
        if (tid < NB) gb[tid] = cb ? atomicAdd(&bcur[tid], cb) : 0;
    }
    __syncthreads();
    // phase 2: rank into LDS stage (sorted by bucket)
    for (int i = tid; i < n; i += 1024) {
        int r = edge[beg + i];
        int c = edge[E + beg + i];
        int b = c >> BSH;
        int slot = atomicAdd(&lcur[b], 1);
        stage[slot] = ((unsigned)r << BSH) | ((unsigned)c & BMASK);
    }
    __syncthreads();
    // phase 3: per-bucket coalesced copy out into the bucket arena
    const int wid = tid >> 6, lane = tid & 63;
    for (int b = wid; b < NB; b += 16) {
        int cb = lcnt[b];
        if (!cb) continue;
        int lb = lsc[b] - cb;
        int g = b * BSTRIDE + gb[b];
        for (int l = lane; l < cb; l += 64)
            bin[g + l] = stage[lb + l];
    }
}

// per-bucket counting sort (bin staged in LDS once) -> CSR + pdesc(float4) +
// fused y0 init (y0 = fp16(dinv * emb))
__global__ __launch_bounds__(256) void csr_kernel(const unsigned* __restrict__ bin,
                                                  const int* __restrict__ bcnt,
                                                  const float* __restrict__ user,
                                                  const float* __restrict__ item,
                                                  int nU,
                                                  float4* __restrict__ pdesc,
                                                  int* __restrict__ row_sorted,
                                                  __half* __restrict__ y0,
                                                  int nN) {
    __shared__ unsigned sbin[BSTRIDE];
    __shared__ int lcnt[256];
    __shared__ int lsc[256];
    __shared__ int lcur[256];
    __shared__ float sdinv[256];
    const int tid = (int)threadIdx.x;
    const int b = (int)blockIdx.x;
    const int abase = b * BSTRIDE;
    const int cnt = bcnt[b];
    lcnt[tid] = 0;
    // stage this bucket's entries in LDS (single global read)
    for (int i = tid; i < cnt; i += 256)
        sbin[i] = bin[abase + i];
    __syncthreads();
    for (int i = tid; i < cnt; i += 256)
        atomicAdd(&lcnt[sbin[i] & BMASK], 1);
    __syncthreads();
    lsc[tid] = lcnt[tid];
    __syncthreads();
    for (int off = 1; off < 256; off <<= 1) {
        int t = (tid >= off) ? lsc[tid - off] : 0;
        __syncthreads();
        lsc[tid] += t;
        __syncthreads();
    }
    const int cb = lcnt[tid];
    const int lb = lsc[tid] - cb;
    lcur[tid] = abase + lb;
    float dv = cb ? rsqrtf((float)cb) : 0.0f;
    sdinv[tid] = dv;
    int node = (b << BSH) + tid;
    if (node < nN) {
        float4 pd;
        pd.x = __int_as_float(abase + lb);
        pd.y = __int_as_float(cb);
        pd.z = dv;
        pd.w = cb ? sqrtf((float)cb) : 0.0f;
        pdesc[node] = pd;
    }
    __syncthreads();
    for (int i = tid; i < cnt; i += 256) {
        unsigned e = sbin[i];
        int c = (int)(e & BMASK);
        int p = atomicAdd(&lcur[c], 1);
        row_sorted[p] = (int)(e >> BSH);
    }
    // fused y0 init: 256 nodes x 8 chunks; chunk qc covers dims 8qc..8qc+7
    const int baseNode = b << BSH;
#pragma unroll
    for (int it = 0; it < 8; ++it) {
        int idx = it * 256 + tid;
        int ln = idx >> 3;
        int node2 = baseNode + ln;
        if (node2 < nN) {
            int qc = idx & 7;
            const float* src = (node2 < nU) ? user + (size_t)node2 * DIM
                                            : item + (size_t)(node2 - nU) * DIM;
            float4 e0 = ((const float4*)src)[qc * 2];
            float4 e1 = ((const float4*)src)[qc * 2 + 1];
            float dvn = sdinv[ln];
            float4 pack;
            __half2* p = (__half2*)&pack;
            p[0] = __floats2half2_rn(dvn * e0.x, dvn * e0.y);
            p[1] = __floats2half2_rn(dvn * e0.z, dvn * e0.w);
            p[2] = __floats2half2_rn(dvn * e1.x, dvn * e1.y);
            p[3] = __floats2half2_rn(dvn * e1.z, dvn * e1.w);
            ((float4*)y0)[(size_t)baseNode * 8 + idx] = pack;
        }
    }
}

// zero the shared pad row (row nN) of the three y tables
__global__ void zero_row_kernel(__half* __restrict__ r1, __half* __restrict__ r2,
                                __half* __restrict__ r3, int nN) {
    int t = threadIdx.x;       // 64 threads
    size_t o = (size_t)nN * DIM + t;
    r1[o] = __float2half(0.0f);
    r2[o] = __float2half(0.0f);
    r3[o] = __float2half(0.0f);
}

// one wave per node; 8 edge-slots x 8 lanes; lane loads float4 (8 halves);
// 32 edges (4KB) in flight; tail slots gather the shared zero row (index nN)
// -> maskless packed-fp16 accumulate.
// LAST fuses the final combine using emb = rdinv*y0 (fallback load if deg==0):
// out = 0.25*(emb + rdinv*(y1+y2) + dinv*sum).
template<bool LAST>
__global__ __launch_bounds__(256) void layer_kernel(const float4* __restrict__ pdesc,
                                                    const int* __restrict__ row_sorted,
                                                    const __half* __restrict__ y_in,
                                                    __half* __restrict__ y_out,
                                                    const float* __restrict__ user,
                                                    const float* __restrict__ item,
                                                    const __half* __restrict__ y_zero,
                                                    const __half* __restrict__ y_prev,
                                                    float* __restrict__ out,
                                                    int nU, int nN) {
    int wave = (int)((blockIdx.x * blockDim.x + threadIdx.x) >> 6);
    int lane = (int)(threadIdx.x & 63);
    if (wave >= nN) return;
    const float4 pd = pdesc[wave];
    const int beg = __float_as_int(pd.x);
    const int n = __float_as_int(pd.y);
    const float dc = pd.z;
    const float rd = pd.w;
    const int zrow = nN;
    const int g = lane >> 3;   // edge slot 0..7
    const int q = lane & 7;    // 16B chunk of the row, 0..7
    const float4* yv = (const float4*)y_in;
    __half2 acc0 = __float2half2_rn(0.0f);
    __half2 acc1 = acc0, acc2 = acc0, acc3 = acc0;
    for (int base = 0; base < n; base += 32) {
        int s = base + g;
        int e = beg + s;
        int i0 = (s      < n) ? row_sorted[e]      : zrow;
        int i1 = (s + 8  < n) ? row_sorted[e + 8]  : zrow;
        int i2 = (s + 16 < n) ? row_sorted[e + 16] : zrow;
        int i3 = (s + 24 < n) ? row_sorted[e + 24] : zrow;
        float4 v0 = yv[(size_t)i0 * 8 + q];
        float4 v1 = yv[(size_t)i1 * 8 + q];
        float4 v2 = yv[(size_t)i2 * 8 + q];
        float4 v3 = yv[(size_t)i3 * 8 + q];
        const __half2* h0 = (const __half2*)&v0;
        const __half2* h1 = (const __half2*)&v1;
        const __half2* h2 = (const __half2*)&v2;
        const __half2* h3 = (const __half2*)&v3;
        acc0 = __hadd2(acc0, h0[0]); acc1 = __hadd2(acc1, h0[1]);
        acc2 = __hadd2(acc2, h0[2]); acc3 = __hadd2(acc3, h0[3]);
        acc0 = __hadd2(acc0, h1[0]); acc1 = __hadd2(acc1, h1[1]);
        acc2 = __hadd2(acc2, h1[2]); acc3 = __hadd2(acc3, h1[3]);
        acc0 = __hadd2(acc0, h2[0]); acc1 = __hadd2(acc1, h2[1]);
        acc2 = __hadd2(acc2, h2[2]); acc3 = __hadd2(acc3, h2[3]);
        acc0 = __hadd2(acc0, h3[0]); acc1 = __hadd2(acc1, h3[1]);
        acc2 = __hadd2(acc2, h3[2]); acc3 = __hadd2(acc3, h3[3]);
    }
    // reduce across the 8 edge-slots (lane bits 3..5), packed fp16
#pragma unroll
    for (int ofs = 8; ofs <= 32; ofs <<= 1) {
        int t0 = __shfl_xor(*reinterpret_cast<int*>(&acc0), ofs);
        int t1 = __shfl_xor(*reinterpret_cast<int*>(&acc1), ofs);
        int t2 = __shfl_xor(*reinterpret_cast<int*>(&acc2), ofs);
        int t3 = __shfl_xor(*reinterpret_cast<int*>(&acc3), ofs);
        acc0 = __hadd2(acc0, *reinterpret_cast<__half2*>(&t0));
        acc1 = __hadd2(acc1, *reinterpret_cast<__half2*>(&t1));
        acc2 = __hadd2(acc2, *reinterpret_cast<__half2*>(&t2));
        acc3 = __hadd2(acc3, *reinterpret_cast<__half2*>(&t3));
    }
    if (g == 0) {
        float2 s0 = __half22float2(acc0);
        float2 s1 = __half22float2(acc1);
        float2 s2 = __half22float2(acc2);
        float2 s3 = __half22float2(acc3);
        if (!LAST) {
            float s = dc * dc;          // y_out = dinv * (dinv * sum)
            float4 pack;
            __half2* ph = (__half2*)&pack;
            ph[0] = __floats2half2_rn(s * s0.x, s * s0.y);
            ph[1] = __floats2half2_rn(s * s1.x, s * s1.y);
            ph[2] = __floats2half2_rn(s * s2.x, s * s2.y);
            ph[3] = __floats2half2_rn(s * s3.x, s * s3.y);
            ((float4*)y_out)[(size_t)wave * 8 + q] = pack;
        } else {
            // out = 0.25*(emb + rdinv*(y1+y2) + dinv*sum); emb = rdinv*y0
            float4 y1r = ((const float4*)y_prev)[(size_t)wave * 8 + q];
            float4 y2r = ((const float4*)y_in)[(size_t)wave * 8 + q];
            const __half2* p1 = (const __half2*)&y1r;
            const __half2* p2 = (const __half2*)&y2r;
            float w[8];
#pragma unroll
            for (int j = 0; j < 4; ++j) {
                float2 u1 = __half22float2(p1[j]);
                float2 u2 = __half22float2(p2[j]);
                w[2 * j]     = u1.x + u2.x;
                w[2 * j + 1] = u1.y + u2.y;
            }
            float emb[8];
            if (rd != 0.0f) {
                float4 y0r = ((const float4*)y_zero)[(size_t)wave * 8 + q];
                const __half2* p0 = (const __half2*)&y0r;
#pragma unroll
                for (int j = 0; j < 4; ++j) {
                    float2 u0 = __half22float2(p0[j]);
                    emb[2 * j]     = rd * u0.x;
                    emb[2 * j + 1] = rd * u0.y;
                }
            } else {
                const float* src = (wave < nU) ? user + (size_t)wave * DIM
                                               : item + (size_t)(wave - nU) * DIM;
                float4 e0 = ((const float4*)src)[q * 2];
                float4 e1 = ((const float4*)src)[q * 2 + 1];
                emb[0] = e0.x; emb[1] = e0.y; emb[2] = e0.z; emb[3] = e0.w;
                emb[4] = e1.x; emb[5] = e1.y; emb[6] = e1.z; emb[7] = e1.w;
            }
            float4 o0, o1;
            o0.x = 0.25f * (emb[0] + rd * w[0] + dc * s0.x);
            o0.y = 0.25f * (emb[1] + rd * w[1] + dc * s0.y);
            o0.z = 0.25f * (emb[2] + rd * w[2] + dc * s1.x);
            o0.w = 0.25f * (emb[3] + rd * w[3] + dc * s1.y);
            o1.x = 0.25f * (emb[4] + rd * w[4] + dc * s2.x);
            o1.y = 0.25f * (emb[5] + rd * w[5] + dc * s2.y);
            o1.z = 0.25f * (emb[6] + rd * w[6] + dc * s3.x);
            o1.w = 0.25f * (emb[7] + rd * w[7] + dc * s3.y);
            float4* o4 = (float4*)(out + (size_t)wave * DIM + q * 8);
            o4[0] = o0;
            o4[1] = o1;
        }
    }
}

// ---------------- host launcher ----------------

extern "C" void kernel_launch(void* const* d_in, const int* in_sizes, int n_in,
                              void* d_out, int out_size, void* d_ws, size_t ws_size,
                              hipStream_t stream) {
    const float* user = (const float*)d_in[0];
    const float* item = (const float*)d_in[1];
    const int*   edge = (const int*)d_in[2];

    const int nU = in_sizes[0] / DIM;
    const int nI = in_sizes[1] / DIM;
    const int nN = nU + nI;
    const int E  = in_sizes[2] / 2;
    const int NB = (nN + 255) / 256;     // 256-node coarse buckets

    float* out = (float*)d_out;

    // workspace carve-up (256B aligned)
    char* ws = (char*)d_ws;
    size_t off = 0;
    auto take = [&](size_t bytes) -> char* {
        char* p = ws + off;
        off = (off + bytes + 255) & ~(size_t)255;
        return p;
    };
    const size_t ytab = (size_t)(nN + 1) * DIM * 2;      // fp16 table + zero row
    const size_t arena = (size_t)NB * BSTRIDE * 4;       // fixed-stride arena
    int*      bcur       = (int*)   take((size_t)NB * 4);
    float4*   pdesc      = (float4*)take((size_t)nN * 16);
    int*      row_sorted = (int*)   take(arena);
    char*     R1 = take(arena > ytab ? arena : ytab);    // bin, then y1
    char*     R2 = take(ytab);                           // y0
    char*     R3 = take(ytab);                           // y2
    unsigned* bin = (unsigned*)R1;
    __half*   y1  = (__half*)R1;
    __half*   y0  = (__half*)R2;
    __half*   y2  = (__half*)R3;
    (void)ws_size; (void)n_in; (void)out_size;

    const int B = 256;
    dim3 blk(B);

    // 1. zero bucket cursors
    zero_ints<<<dim3((NB + B - 1) / B), blk, 0, stream>>>(bcur, NB);
    // 2. LDS-staged scatter into fixed-stride bucket arenas
    bin_kernel<<<dim3((E + BINC - 1) / BINC), dim3(1024), 0, stream>>>(edge, E, bcur, bin, NB);
    // 3. per-bucket counting sort -> CSR + pdesc + fused y0 init
    csr_kernel<<<dim3(NB), blk, 0, stream>>>(bin, bcur, user, item, nU,
                                             pdesc, row_sorted, y0, nN);
    // 3b. zero the shared pad row (after bin is consumed; y1 aliases bin)
    zero_row_kernel<<<dim3(1), dim3(64), 0, stream>>>(y0, y1, y2, nN);

    // 4. three propagation layers; layer 3 fuses the final combine
    dim3 lgrid((nN + 3) / 4);   // 4 waves (nodes) per 256-thread block
    layer_kernel<false><<<lgrid, blk, 0, stream>>>(pdesc, row_sorted, y0, y1,
                                                   nullptr, nullptr, nullptr, nullptr, nullptr,
                                                   nU, nN);
    layer_kernel<false><<<lgrid, blk, 0, stream>>>(pdesc, row_sorted, y1, y2,
                                                   nullptr, nullptr, nullptr, nullptr, nullptr,
                                                   nU, nN);
    layer_kernel<true ><<<lgrid, blk, 0, stream>>>(pdesc, row_sorted, y2, nullptr,
                                                   user, item, y0, y1, out,
                                                   nU, nN);
}